// Round 5
// baseline (241.973 us; speedup 1.0000x reference)
//
#include <hip/hip_runtime.h>
#include <stdint.h>

#define B_SZ 32
#define T_SZ 300
#define F_IN 3072
#define F_HID 410
#define F_OUT 10
#define M_SZ (B_SZ * T_SZ)              // 9600
#define N_PAD 448                       // a1 row stride = gemm1 N (7 x 64)
#define KW (F_IN / 32)                  // 96 bit-words per spike row
#define TOTAL_ELEMS (B_SZ * T_SZ * F_IN)
#define N_WORDS (TOTAL_ELEMS / 32)      // 921600
#define A2_STRIDE 16
#define NCHUNK 10
#define CLEN 30

// f32(exp(f32(-0.1))) — PSP decay, matches XLA's correctly-rounded exp
#define DECAY 0.90483741803595957f
#define THETA 10.0f

typedef __attribute__((ext_vector_type(8))) int i32x8;
typedef __attribute__((ext_vector_type(16))) float f32x16;

__device__ __forceinline__ uint32_t rotl32(uint32_t x, uint32_t r) {
  return (x << r) | (x >> (32u - r));
}

// JAX threefry2x32, key = (0, 42)
__device__ __forceinline__ void threefry2x32(uint32_t& x0, uint32_t& x1) {
  const uint32_t ks0 = 0u;
  const uint32_t ks1 = 42u;
  const uint32_t ks2 = 0x1BD11BDAu ^ 0u ^ 42u;
  x0 += ks0; x1 += ks1;
#define TF_ROUND(r) { x0 += x1; x1 = rotl32(x1, (r)); x1 ^= x0; }
  TF_ROUND(13) TF_ROUND(15) TF_ROUND(26) TF_ROUND(6)
  x0 += ks1; x1 += ks2 + 1u;
  TF_ROUND(17) TF_ROUND(29) TF_ROUND(16) TF_ROUND(24)
  x0 += ks2; x1 += ks0 + 2u;
  TF_ROUND(13) TF_ROUND(15) TF_ROUND(26) TF_ROUND(6)
  x0 += ks0; x1 += ks1 + 3u;
  TF_ROUND(17) TF_ROUND(29) TF_ROUND(16) TF_ROUND(24)
  x0 += ks1; x1 += ks2 + 4u;
  TF_ROUND(13) TF_ROUND(15) TF_ROUND(26) TF_ROUND(6)
  x0 += ks2; x1 += ks0 + 5u;
#undef TF_ROUND
}

__device__ __forceinline__ float u01(uint32_t bits) {
  return __uint_as_float((bits >> 9) | 0x3F800000u) - 1.0f;
}

// Partitionable threefry: ctr=(0,i), bits = o0^o1. One thread per 32-bit word.
__global__ __launch_bounds__(256) void rng_spikes(const float* __restrict__ inp,
                                                  uint32_t* __restrict__ sbits) {
  uint32_t j = blockIdx.x * 256u + threadIdx.x;
  uint32_t base = j << 5;
  uint32_t b = base / (uint32_t)(T_SZ * F_IN);
  uint32_t f = base % (uint32_t)F_IN;
  const float* p = inp + b * F_IN + f;
  float pr[32];
#pragma unroll
  for (int q = 0; q < 8; ++q) {
    float4 v = ((const float4*)p)[q];
    pr[q * 4 + 0] = v.x; pr[q * 4 + 1] = v.y; pr[q * 4 + 2] = v.z; pr[q * 4 + 3] = v.w;
  }
  uint32_t w = 0u;
#pragma unroll
  for (uint32_t k = 0; k < 32u; ++k) {
    uint32_t x0 = 0u, x1 = base + k;
    threefry2x32(x0, x1);
    float u = u01(x0 ^ x1);
    w |= (u < pr[k]) ? (1u << k) : 0u;
  }
  sbits[j] = w;
}

// W1 fp32 [410][3072] -> W1f8 e4m3 [448][3072], rows >= 410 zeroed.
__global__ __launch_bounds__(256) void w1_to_fp8(const float* __restrict__ W1,
                                                 uint8_t* __restrict__ W1f8) {
  int idx = blockIdx.x * 256 + threadIdx.x;   // 448*3072/8 = 172032 threads
  int g = idx * 8;
  int row = g / F_IN;
  int col = g - row * F_IN;
  uint32_t d0 = 0u, d1 = 0u;
  if (row < F_HID) {
    const float* s = W1 + (size_t)row * F_IN + col;
    float4 v0 = ((const float4*)s)[0];
    float4 v1 = ((const float4*)s)[1];
    int t0 = __builtin_amdgcn_cvt_pk_fp8_f32(v0.x, v0.y, 0, false);
    t0 = __builtin_amdgcn_cvt_pk_fp8_f32(v0.z, v0.w, t0, true);
    int t1 = __builtin_amdgcn_cvt_pk_fp8_f32(v1.x, v1.y, 0, false);
    t1 = __builtin_amdgcn_cvt_pk_fp8_f32(v1.z, v1.w, t1, true);
    d0 = (uint32_t)t0; d1 = (uint32_t)t1;
  }
  *(uint2*)(W1f8 + (size_t)row * F_IN + col) = make_uint2(d0, d1);
}

// a1[m][n] = sum_k spike(m,k) * W1[n][k], MX-fp8 MFMA 32x32x64 (scales=127=2^0).
// BM=64, BN=64, BK=128, grid 150x7 = 1050 blocks (vs R4's 300 - TLP was the
// bottleneck). 2 waves/block split K (wave kh does one K-64 step per kb);
// LDS f32 reduction at the end. A bits transposed in LDS (conflict-free b32);
// B fp8 XOR-swizzled 16B chunks. Register prefetch of kb+1. LDS 16.5 KB.
__global__ __launch_bounds__(128, 4) void gemm1(const uint32_t* __restrict__ sbits,
                                                const uint8_t* __restrict__ W1f8,
                                                float* __restrict__ a1) {
  __shared__ union U {
    struct { uint32_t bits[4 * 64]; uint8_t B[64 * 128]; } s;  // 1 KB + 8 KB
    float red[64 * 64];                                        // 16 KB (aliased)
  } sm;

  const int tid = threadIdx.x;
  const int m0 = blockIdx.x * 64;
  const int n0 = blockIdx.y * 64;
  const int kh = tid >> 6;          // wave = K-half of each BK
  const int lane = tid & 63;
  const int l31 = lane & 31, lh = lane >> 5;
  const int r = tid & 63, cs = tid >> 6;   // staging: row, chunk-segment

  f32x16 acc[2][2];
#pragma unroll
  for (int i = 0; i < 2; ++i)
#pragma unroll
    for (int j = 0; j < 2; ++j)
#pragma unroll
      for (int e = 0; e < 16; ++e)
        acc[i][j][e] = 0.0f;

  // prefetch kb = 0
  uint2 apre = *(const uint2*)&sbits[(size_t)(m0 + r) * KW + 2 * cs];
  uint4 bpre[4];
#pragma unroll
  for (int i = 0; i < 4; ++i)
    bpre[i] = *(const uint4*)&W1f8[(size_t)(n0 + r) * F_IN + (cs * 4 + i) * 16];

  for (int kb = 0; kb < F_IN / 128; ++kb) {
    __syncthreads();
    // A bits, transposed: bits[word][row] -> conflict-free reads
    sm.s.bits[(2 * cs + 0) * 64 + r] = apre.x;
    sm.s.bits[(2 * cs + 1) * 64 + r] = apre.y;
#pragma unroll
    for (int i = 0; i < 4; ++i) {
      int c = cs * 4 + i;
      *(uint4*)&sm.s.B[r * 128 + ((c ^ (r & 7)) << 4)] = bpre[i];
    }
    __syncthreads();
    if (kb < F_IN / 128 - 1) {
      apre = *(const uint2*)&sbits[(size_t)(m0 + r) * KW + (kb + 1) * 4 + 2 * cs];
#pragma unroll
      for (int i = 0; i < 4; ++i)
        bpre[i] = *(const uint4*)&W1f8[(size_t)(n0 + r) * F_IN + (kb + 1) * 128 + (cs * 4 + i) * 16];
    }
    // this wave's K-64 step: k = kb*128 + kh*64
    i32x8 bfr[2];
#pragma unroll
    for (int nt = 0; nt < 2; ++nt) {
      int row = nt * 32 + l31;
      int cb = kh * 4 + lh * 2;
      uint4 u0 = *(uint4*)&sm.s.B[row * 128 + (((cb + 0) ^ (row & 7)) << 4)];
      uint4 u1 = *(uint4*)&sm.s.B[row * 128 + (((cb + 1) ^ (row & 7)) << 4)];
      bfr[nt][0] = u0.x; bfr[nt][1] = u0.y; bfr[nt][2] = u0.z; bfr[nt][3] = u0.w;
      bfr[nt][4] = u1.x; bfr[nt][5] = u1.y; bfr[nt][6] = u1.z; bfr[nt][7] = u1.w;
    }
#pragma unroll
    for (int mt = 0; mt < 2; ++mt) {
      uint32_t w = sm.s.bits[(kh * 2 + lh) * 64 + mt * 32 + l31];
      i32x8 afr;
#pragma unroll
      for (int j = 0; j < 8; ++j) {
        uint32_t n = (w >> (4 * j)) & 15u;
        afr[j] = (int)(((n * 0x204081u) & 0x01010101u) * 0x38u);
      }
#pragma unroll
      for (int nt = 0; nt < 2; ++nt)
        acc[mt][nt] = __builtin_amdgcn_mfma_scale_f32_32x32x64_f8f6f4(
            afr, bfr[nt], acc[mt][nt], 0, 0, 0, 127, 0, 127);
    }
  }
  // cross-wave K reduction via LDS (red aliases bits/B - all reads are done)
  __syncthreads();
  if (kh == 1) {
#pragma unroll
    for (int mt = 0; mt < 2; ++mt)
#pragma unroll
      for (int nt = 0; nt < 2; ++nt)
#pragma unroll
        for (int rg = 0; rg < 16; ++rg) {
          int row = mt * 32 + (rg & 3) + 8 * (rg >> 2) + 4 * lh;
          sm.red[row * 64 + nt * 32 + l31] = acc[mt][nt][rg];
        }
  }
  __syncthreads();
  if (kh == 0) {
#pragma unroll
    for (int mt = 0; mt < 2; ++mt)
#pragma unroll
      for (int nt = 0; nt < 2; ++nt)
#pragma unroll
        for (int rg = 0; rg < 16; ++rg) {
          int row = mt * 32 + (rg & 3) + 8 * (rg >> 2) + 4 * lh;
          int col = nt * 32 + l31;
          a1[(size_t)(m0 + row) * N_PAD + n0 + col] = acc[mt][nt][rg] + sm.red[row * 64 + col];
        }
  }
}

// PSP phase A: per-(b,chunk,o) partial scan from 0; partials overwrite a1;
// chunk finals -> fin[b][c][o].
__global__ __launch_bounds__(256) void psp1_partial(float* __restrict__ a1,
                                                    float* __restrict__ fin) {
  int idx = blockIdx.x * 256 + threadIdx.x;   // 32*10*448 = 143360
  if (idx >= B_SZ * NCHUNK * N_PAD) return;
  int o = idx % N_PAD;
  int bc = idx / N_PAD;
  int c = bc % NCHUNK;
  int b = bc / NCHUNK;
  float* p = a1 + ((size_t)(b * T_SZ + c * CLEN)) * N_PAD + o;
  float u = 0.0f;
#pragma unroll
  for (int i = 0; i < CLEN; ++i) {
    u = __fadd_rn(__fmul_rn(DECAY, u), p[(size_t)i * N_PAD]);
    p[(size_t)i * N_PAD] = u;
  }
  fin[(size_t)bc * N_PAD + o] = u;
}

// PSP phase B: F(c) = pf(c) + decay^30 * F(c-1), in place on fin.
__global__ __launch_bounds__(256) void psp1_combine(float* __restrict__ fin) {
  int idx = blockIdx.x * 256 + threadIdx.x;   // 32*448 = 14336
  if (idx >= B_SZ * N_PAD) return;
  int o = idx % N_PAD;
  int b = idx / N_PAD;
  float d30 = 1.0f;
#pragma unroll
  for (int i = 0; i < CLEN; ++i) d30 *= DECAY;
  float F = 0.0f;
  float* f = fin + (size_t)b * NCHUNK * N_PAD + o;
  for (int c = 0; c < NCHUNK; ++c) {
    F = f[(size_t)c * N_PAD] + d30 * F;
    f[(size_t)c * N_PAD] = F;
  }
}

// Fused PSP phase C + layer-2 GEMM: one wave per (b,t) row; W2 staged in LDS.
__global__ __launch_bounds__(256) void apply_gemm2(const float* __restrict__ a1,
                                                   const float* __restrict__ fin,
                                                   const float* __restrict__ W2,
                                                   float* __restrict__ a2) {
  __shared__ float sW2[F_OUT * F_HID];   // 16.4 KB
  for (int i = threadIdx.x; i < F_OUT * F_HID; i += 256) sW2[i] = W2[i];
  __syncthreads();
  int m = blockIdx.x * 4 + (threadIdx.x >> 6);
  int lane = threadIdx.x & 63;
  int b = m / T_SZ, t = m % T_SZ;
  int c = t / CLEN, tl = t % CLEN;
  float dp = DECAY;
  for (int i = 0; i < tl; ++i) dp *= DECAY;   // decay^(tl+1), wave-uniform
  float p[F_OUT];
#pragma unroll
  for (int o = 0; o < F_OUT; ++o) p[o] = 0.0f;
#pragma unroll
  for (int j = 0; j < 7; ++j) {
    int hh = lane + j * 64;
    float u = a1[(size_t)m * N_PAD + hh];
    if (c > 0) u = __fadd_rn(u, __fmul_rn(dp, fin[((size_t)b * NCHUNK + c - 1) * N_PAD + hh]));
    bool valid = hh < F_HID;
    float s = (u >= THETA && valid) ? 1.0f : 0.0f;
    int hcl = valid ? hh : 0;
#pragma unroll
    for (int o = 0; o < F_OUT; ++o) p[o] = fmaf(s, sW2[o * F_HID + hcl], p[o]);
  }
#pragma unroll
  for (int o = 0; o < F_OUT; ++o)
#pragma unroll
    for (int s = 1; s < 64; s <<= 1) p[o] += __shfl_xor(p[o], s, 64);
  if (lane < F_OUT) a2[(size_t)m * A2_STRIDE + lane] = p[lane];
}

// Layer-2 PSP, chunked, one block per batch; lanes (o,c) in [10x10].
// Chunk values held in registers to pipeline the loads.
__global__ __launch_bounds__(128) void psp2(const float* __restrict__ a2,
                                            float* __restrict__ out) {
  __shared__ float chf[NCHUNK][F_OUT];
  __shared__ float seed[NCHUNK][F_OUT];
  int b = blockIdx.x;
  int tid = threadIdx.x;
  int o = tid / NCHUNK, c = tid % NCHUNK;
  const float* p = a2 + ((size_t)(b * T_SZ + c * CLEN)) * A2_STRIDE + o;
  float v[CLEN];
  float pa[CLEN];
  if (tid < F_OUT * NCHUNK) {
#pragma unroll
    for (int i = 0; i < CLEN; ++i) v[i] = p[(size_t)i * A2_STRIDE];
    float u = 0.0f;
#pragma unroll
    for (int i = 0; i < CLEN; ++i) {
      u = __fadd_rn(__fmul_rn(DECAY, u), v[i]);
      pa[i] = u;
    }
    chf[c][o] = u;
  }
  __syncthreads();
  if (tid < F_OUT) {
    float d30 = 1.0f;
#pragma unroll
    for (int i = 0; i < CLEN; ++i) d30 *= DECAY;
    float F = 0.0f;
    for (int cc = 0; cc < NCHUNK; ++cc) {
      F = chf[cc][tid] + d30 * F;
      seed[cc][tid] = F;
    }
  }
  __syncthreads();
  if (tid < F_OUT * NCHUNK) {
    float F = (c == 0) ? 0.0f : seed[c - 1][o];
    float dp = DECAY;
    float* q = out + (size_t)b * F_OUT * T_SZ + (size_t)o * T_SZ + c * CLEN;
#pragma unroll
    for (int i = 0; i < CLEN; ++i) {
      float u = (c == 0) ? pa[i] : __fadd_rn(pa[i], __fmul_rn(dp, F));
      q[i] = (u >= THETA) ? 1.0f : 0.0f;
      dp *= DECAY;
    }
  }
}

extern "C" void kernel_launch(void* const* d_in, const int* in_sizes, int n_in,
                              void* d_out, int out_size, void* d_ws, size_t ws_size,
                              hipStream_t stream) {
  const float* inp = (const float*)d_in[0];  // [32,3,32,32]
  const float* W1  = (const float*)d_in[1];  // [410,3072]
  const float* W2  = (const float*)d_in[2];  // [10,410]
  float* out = (float*)d_out;                // [32,10,300]
  char* ws = (char*)d_ws;
  // ws: W1f8 1376256 | sbits 3686400 | a1 17203200 | fin 573440 | a2 614400
  uint8_t* W1f8 = (uint8_t*)(ws);
  uint32_t* sbits = (uint32_t*)(ws + 1376256);
  float* a1 = (float*)(ws + 1376256 + 3686400);
  float* fin = a1 + (size_t)M_SZ * N_PAD;
  float* a2 = fin + (size_t)B_SZ * NCHUNK * N_PAD;

  w1_to_fp8<<<dim3((N_PAD * F_IN / 8) / 256), dim3(256), 0, stream>>>(W1, W1f8);
  rng_spikes<<<dim3(N_WORDS / 256), dim3(256), 0, stream>>>(inp, sbits);
  gemm1<<<dim3(M_SZ / 64, N_PAD / 64), dim3(128), 0, stream>>>(sbits, W1f8, a1);
  psp1_partial<<<dim3((B_SZ * NCHUNK * N_PAD) / 256), dim3(256), 0, stream>>>(a1, fin);
  psp1_combine<<<dim3((B_SZ * N_PAD) / 256), dim3(256), 0, stream>>>(fin);
  apply_gemm2<<<dim3(M_SZ / 4), dim3(256), 0, stream>>>(a1, fin, W2, a2);
  psp2<<<dim3(B_SZ), dim3(128), 0, stream>>>(a2, out);
}

// Round 6
// 237.877 us; speedup vs baseline: 1.0172x; 1.0172x over previous
//
#include <hip/hip_runtime.h>
#include <stdint.h>

#define B_SZ 32
#define T_SZ 300
#define F_IN 3072
#define F_HID 410
#define F_OUT 10
#define M_SZ (B_SZ * T_SZ)              // 9600
#define N_PAD 448                       // a1 row stride = gemm1 N (7 x 64)
#define KW (F_IN / 32)                  // 96 bit-words per spike row
#define TOTAL_ELEMS (B_SZ * T_SZ * F_IN)
#define N_WORDS (TOTAL_ELEMS / 32)      // 921600
#define A2_STRIDE 16
#define NCHUNK 10
#define CLEN 30
#define W1_BLOCKS 672                   // 448*3072/8/256
#define RNG_BLOCKS 3600                 // 921600/256

// f32(exp(f32(-0.1))) — PSP decay, matches XLA's correctly-rounded exp
#define DECAY 0.90483741803595957f
#define THETA 10.0f

typedef __attribute__((ext_vector_type(8))) int i32x8;
typedef __attribute__((ext_vector_type(16))) float f32x16;

__device__ __forceinline__ uint32_t rotl32(uint32_t x, uint32_t r) {
  return (x << r) | (x >> (32u - r));
}

// JAX threefry2x32, key = (0, 42)
__device__ __forceinline__ void threefry2x32(uint32_t& x0, uint32_t& x1) {
  const uint32_t ks0 = 0u;
  const uint32_t ks1 = 42u;
  const uint32_t ks2 = 0x1BD11BDAu ^ 0u ^ 42u;
  x0 += ks0; x1 += ks1;
#define TF_ROUND(r) { x0 += x1; x1 = rotl32(x1, (r)); x1 ^= x0; }
  TF_ROUND(13) TF_ROUND(15) TF_ROUND(26) TF_ROUND(6)
  x0 += ks1; x1 += ks2 + 1u;
  TF_ROUND(17) TF_ROUND(29) TF_ROUND(16) TF_ROUND(24)
  x0 += ks2; x1 += ks0 + 2u;
  TF_ROUND(13) TF_ROUND(15) TF_ROUND(26) TF_ROUND(6)
  x0 += ks0; x1 += ks1 + 3u;
  TF_ROUND(17) TF_ROUND(29) TF_ROUND(16) TF_ROUND(24)
  x0 += ks1; x1 += ks2 + 4u;
  TF_ROUND(13) TF_ROUND(15) TF_ROUND(26) TF_ROUND(6)
  x0 += ks2; x1 += ks0 + 5u;
#undef TF_ROUND
}

__device__ __forceinline__ float u01(uint32_t bits) {
  return __uint_as_float((bits >> 9) | 0x3F800000u) - 1.0f;
}

// Merged prep: blocks [0,672) convert W1 fp32 -> e4m3 (rows >=410 zeroed);
// blocks [672, 4272) run partitionable threefry rate-encode (1 thread = 1
// 32-bit spike word, ctr=(0,i), bits=o0^o1).
__global__ __launch_bounds__(256) void prep(const float* __restrict__ inp,
                                            const float* __restrict__ W1,
                                            uint8_t* __restrict__ W1f8,
                                            uint32_t* __restrict__ sbits) {
  if (blockIdx.x < W1_BLOCKS) {
    int idx = blockIdx.x * 256 + threadIdx.x;
    int g = idx * 8;
    int row = g / F_IN;
    int col = g - row * F_IN;
    uint32_t d0 = 0u, d1 = 0u;
    if (row < F_HID) {
      const float* s = W1 + (size_t)row * F_IN + col;
      float4 v0 = ((const float4*)s)[0];
      float4 v1 = ((const float4*)s)[1];
      int t0 = __builtin_amdgcn_cvt_pk_fp8_f32(v0.x, v0.y, 0, false);
      t0 = __builtin_amdgcn_cvt_pk_fp8_f32(v0.z, v0.w, t0, true);
      int t1 = __builtin_amdgcn_cvt_pk_fp8_f32(v1.x, v1.y, 0, false);
      t1 = __builtin_amdgcn_cvt_pk_fp8_f32(v1.z, v1.w, t1, true);
      d0 = (uint32_t)t0; d1 = (uint32_t)t1;
    }
    *(uint2*)(W1f8 + (size_t)row * F_IN + col) = make_uint2(d0, d1);
  } else {
    uint32_t j = (blockIdx.x - W1_BLOCKS) * 256u + threadIdx.x;
    uint32_t base = j << 5;
    uint32_t b = base / (uint32_t)(T_SZ * F_IN);
    uint32_t f = base % (uint32_t)F_IN;
    const float* p = inp + b * F_IN + f;
    float pr[32];
#pragma unroll
    for (int q = 0; q < 8; ++q) {
      float4 v = ((const float4*)p)[q];
      pr[q * 4 + 0] = v.x; pr[q * 4 + 1] = v.y; pr[q * 4 + 2] = v.z; pr[q * 4 + 3] = v.w;
    }
    uint32_t w = 0u;
#pragma unroll
    for (uint32_t k = 0; k < 32u; ++k) {
      uint32_t x0 = 0u, x1 = base + k;
      threefry2x32(x0, x1);
      float u = u01(x0 ^ x1);
      w |= (u < pr[k]) ? (1u << k) : 0u;
    }
    sbits[j] = w;
  }
}

// a1[m][n] = sum_k spike(m,k) * W1[n][k], MX-fp8 MFMA 32x32x64 (scales=127=2^0).
// BM=64, BN=64, BK=256 (12 iters), grid 150x7=1050 blocks, 256 thr = 4 waves
// in a 2x2 grid of 32x32 wave tiles -> acc = 16 AGPR (R5 spilled at 64 under
// a 128-reg cap; this keeps total regs ~90 < (256,3) cap of 170).
// A: bitpacked words transposed in LDS [word][row] (conflict-free b32),
// expanded to fp8 at frag read (mul-spread). B: fp8 LDS, 16B chunks XOR-
// swizzled phys=c^(row&15). Register prefetch of kb+1 (18 VGPR).
__global__ __launch_bounds__(256, 3) void gemm1(const uint32_t* __restrict__ sbits,
                                                const uint8_t* __restrict__ W1f8,
                                                float* __restrict__ a1) {
  __shared__ uint32_t sBitsT[8][64];    // 2 KB
  __shared__ uint8_t sB[64 * 256];      // 16 KB

  const int tid = threadIdx.x;
  const int m0 = blockIdx.x * 64;
  const int n0 = blockIdx.y * 64;
  const int wv = tid >> 6, lane = tid & 63;
  const int wm = (wv & 1) * 32, wn = (wv >> 1) * 32;
  const int l31 = lane & 31, lh = lane >> 5;
  const int r = tid & 63;          // staging row
  const int seg = tid >> 6;        // staging segment 0..3

  f32x16 acc;
#pragma unroll
  for (int e = 0; e < 16; ++e) acc[e] = 0.0f;

  // prefetch kb = 0
  uint2 apre = *(const uint2*)&sbits[(size_t)(m0 + r) * KW + seg * 2];
  uint4 bpre[4];
#pragma unroll
  for (int i = 0; i < 4; ++i)
    bpre[i] = *(const uint4*)&W1f8[(size_t)(n0 + r) * F_IN + (seg * 4 + i) * 16];

  for (int kb = 0; kb < F_IN / 256; ++kb) {
    __syncthreads();
    sBitsT[seg * 2 + 0][r] = apre.x;
    sBitsT[seg * 2 + 1][r] = apre.y;
#pragma unroll
    for (int i = 0; i < 4; ++i) {
      int c = seg * 4 + i;
      *(uint4*)&sB[r * 256 + ((c ^ (r & 15)) << 4)] = bpre[i];
    }
    __syncthreads();
    if (kb < F_IN / 256 - 1) {
      apre = *(const uint2*)&sbits[(size_t)(m0 + r) * KW + (kb + 1) * 8 + seg * 2];
#pragma unroll
      for (int i = 0; i < 4; ++i)
        bpre[i] = *(const uint4*)&W1f8[(size_t)(n0 + r) * F_IN + (kb + 1) * 256 + (seg * 4 + i) * 16];
    }
#pragma unroll
    for (int sub = 0; sub < 4; ++sub) {
      // B frag: lane holds B[n = wn+l31][k = sub*64 + lh*32 + 0..31]
      int row = wn + l31;
      int cb = sub * 4 + lh * 2;
      uint4 u0 = *(uint4*)&sB[row * 256 + (((cb + 0) ^ (row & 15)) << 4)];
      uint4 u1 = *(uint4*)&sB[row * 256 + (((cb + 1) ^ (row & 15)) << 4)];
      i32x8 bfr;
      bfr[0] = u0.x; bfr[1] = u0.y; bfr[2] = u0.z; bfr[3] = u0.w;
      bfr[4] = u1.x; bfr[5] = u1.y; bfr[6] = u1.z; bfr[7] = u1.w;
      // A frag: lane holds A[m = wm+l31][k = sub*64 + lh*32 + 0..31]
      uint32_t w = sBitsT[sub * 2 + lh][wm + l31];
      i32x8 afr;
#pragma unroll
      for (int j = 0; j < 8; ++j) {
        uint32_t n = (w >> (4 * j)) & 15u;
        afr[j] = (int)(((n * 0x204081u) & 0x01010101u) * 0x38u);
      }
      acc = __builtin_amdgcn_mfma_scale_f32_32x32x64_f8f6f4(
          afr, bfr, acc, 0, 0, 0, 127, 0, 127);
    }
  }
  // epilogue: C/D 32x32: col = lane&31, row = (reg&3) + 8*(reg>>2) + 4*(lane>>5)
  int col = n0 + wn + l31;
#pragma unroll
  for (int rg = 0; rg < 16; ++rg) {
    int row = m0 + wm + (rg & 3) + 8 * (rg >> 2) + 4 * lh;
    a1[(size_t)row * N_PAD + col] = acc[rg];
  }
}

// PSP phase A: per-(b,chunk,o) partial scan from 0; partials overwrite a1;
// chunk finals -> fin[b][c][o].
__global__ __launch_bounds__(256) void psp1_partial(float* __restrict__ a1,
                                                    float* __restrict__ fin) {
  int idx = blockIdx.x * 256 + threadIdx.x;   // 32*10*448 = 143360
  if (idx >= B_SZ * NCHUNK * N_PAD) return;
  int o = idx % N_PAD;
  int bc = idx / N_PAD;
  int c = bc % NCHUNK;
  int b = bc / NCHUNK;
  float* p = a1 + ((size_t)(b * T_SZ + c * CLEN)) * N_PAD + o;
  float u = 0.0f;
#pragma unroll
  for (int i = 0; i < CLEN; ++i) {
    u = __fadd_rn(__fmul_rn(DECAY, u), p[(size_t)i * N_PAD]);
    p[(size_t)i * N_PAD] = u;
  }
  fin[(size_t)bc * N_PAD + o] = u;
}

// PSP phase B: F(c) = pf(c) + decay^30 * F(c-1), in place on fin.
__global__ __launch_bounds__(256) void psp1_combine(float* __restrict__ fin) {
  int idx = blockIdx.x * 256 + threadIdx.x;   // 32*448 = 14336
  if (idx >= B_SZ * N_PAD) return;
  int o = idx % N_PAD;
  int b = idx / N_PAD;
  float d30 = 1.0f;
#pragma unroll
  for (int i = 0; i < CLEN; ++i) d30 *= DECAY;
  float F = 0.0f;
  float* f = fin + (size_t)b * NCHUNK * N_PAD + o;
  for (int c = 0; c < NCHUNK; ++c) {
    F = f[(size_t)c * N_PAD] + d30 * F;
    f[(size_t)c * N_PAD] = F;
  }
}

// Fused PSP phase C + layer-2 GEMM: one wave per (b,t) row; W2 staged in LDS.
__global__ __launch_bounds__(256) void apply_gemm2(const float* __restrict__ a1,
                                                   const float* __restrict__ fin,
                                                   const float* __restrict__ W2,
                                                   float* __restrict__ a2) {
  __shared__ float sW2[F_OUT * F_HID];   // 16.4 KB
  for (int i = threadIdx.x; i < F_OUT * F_HID; i += 256) sW2[i] = W2[i];
  __syncthreads();
  int m = blockIdx.x * 4 + (threadIdx.x >> 6);
  int lane = threadIdx.x & 63;
  int b = m / T_SZ, t = m % T_SZ;
  int c = t / CLEN, tl = t % CLEN;
  float dp = DECAY;
  for (int i = 0; i < tl; ++i) dp *= DECAY;   // decay^(tl+1), wave-uniform
  float p[F_OUT];
#pragma unroll
  for (int o = 0; o < F_OUT; ++o) p[o] = 0.0f;
#pragma unroll
  for (int j = 0; j < 7; ++j) {
    int hh = lane + j * 64;
    float u = a1[(size_t)m * N_PAD + hh];
    if (c > 0) u = __fadd_rn(u, __fmul_rn(dp, fin[((size_t)b * NCHUNK + c - 1) * N_PAD + hh]));
    bool valid = hh < F_HID;
    float s = (u >= THETA && valid) ? 1.0f : 0.0f;
    int hcl = valid ? hh : 0;
#pragma unroll
    for (int o = 0; o < F_OUT; ++o) p[o] = fmaf(s, sW2[o * F_HID + hcl], p[o]);
  }
#pragma unroll
  for (int o = 0; o < F_OUT; ++o)
#pragma unroll
    for (int s = 1; s < 64; s <<= 1) p[o] += __shfl_xor(p[o], s, 64);
  if (lane < F_OUT) a2[(size_t)m * A2_STRIDE + lane] = p[lane];
}

// Layer-2 PSP, chunked, one block per batch; lanes (o,c) in [10x10].
__global__ __launch_bounds__(128) void psp2(const float* __restrict__ a2,
                                            float* __restrict__ out) {
  __shared__ float chf[NCHUNK][F_OUT];
  __shared__ float seed[NCHUNK][F_OUT];
  int b = blockIdx.x;
  int tid = threadIdx.x;
  int o = tid / NCHUNK, c = tid % NCHUNK;
  const float* p = a2 + ((size_t)(b * T_SZ + c * CLEN)) * A2_STRIDE + o;
  float v[CLEN];
  float pa[CLEN];
  if (tid < F_OUT * NCHUNK) {
#pragma unroll
    for (int i = 0; i < CLEN; ++i) v[i] = p[(size_t)i * A2_STRIDE];
    float u = 0.0f;
#pragma unroll
    for (int i = 0; i < CLEN; ++i) {
      u = __fadd_rn(__fmul_rn(DECAY, u), v[i]);
      pa[i] = u;
    }
    chf[c][o] = u;
  }
  __syncthreads();
  if (tid < F_OUT) {
    float d30 = 1.0f;
#pragma unroll
    for (int i = 0; i < CLEN; ++i) d30 *= DECAY;
    float F = 0.0f;
    for (int cc = 0; cc < NCHUNK; ++cc) {
      F = chf[cc][tid] + d30 * F;
      seed[cc][tid] = F;
    }
  }
  __syncthreads();
  if (tid < F_OUT * NCHUNK) {
    float F = (c == 0) ? 0.0f : seed[c - 1][o];
    float dp = DECAY;
    float* q = out + (size_t)b * F_OUT * T_SZ + (size_t)o * T_SZ + c * CLEN;
#pragma unroll
    for (int i = 0; i < CLEN; ++i) {
      float u = (c == 0) ? pa[i] : __fadd_rn(pa[i], __fmul_rn(dp, F));
      q[i] = (u >= THETA) ? 1.0f : 0.0f;
      dp *= DECAY;
    }
  }
}

extern "C" void kernel_launch(void* const* d_in, const int* in_sizes, int n_in,
                              void* d_out, int out_size, void* d_ws, size_t ws_size,
                              hipStream_t stream) {
  const float* inp = (const float*)d_in[0];  // [32,3,32,32]
  const float* W1  = (const float*)d_in[1];  // [410,3072]
  const float* W2  = (const float*)d_in[2];  // [10,410]
  float* out = (float*)d_out;                // [32,10,300]
  char* ws = (char*)d_ws;
  // ws: W1f8 1376256 | sbits 3686400 | a1 17203200 | fin 573440 | a2 614400
  uint8_t* W1f8 = (uint8_t*)(ws);
  uint32_t* sbits = (uint32_t*)(ws + 1376256);
  float* a1 = (float*)(ws + 1376256 + 3686400);
  float* fin = a1 + (size_t)M_SZ * N_PAD;
  float* a2 = fin + (size_t)B_SZ * NCHUNK * N_PAD;

  prep<<<dim3(W1_BLOCKS + RNG_BLOCKS), dim3(256), 0, stream>>>(inp, W1, W1f8, sbits);
  gemm1<<<dim3(M_SZ / 64, N_PAD / 64), dim3(256), 0, stream>>>(sbits, W1f8, a1);
  psp1_partial<<<dim3((B_SZ * NCHUNK * N_PAD) / 256), dim3(256), 0, stream>>>(a1, fin);
  psp1_combine<<<dim3((B_SZ * N_PAD) / 256), dim3(256), 0, stream>>>(fin);
  apply_gemm2<<<dim3(M_SZ / 4), dim3(256), 0, stream>>>(a1, fin, W2, a2);
  psp2<<<dim3(B_SZ), dim3(128), 0, stream>>>(a2, out);
}

// Round 7
// 181.270 us; speedup vs baseline: 1.3349x; 1.3123x over previous
//
#include <hip/hip_runtime.h>
#include <stdint.h>

#define B_SZ 32
#define T_SZ 300
#define F_IN 3072
#define F_HID 410
#define F_OUT 10
#define M_SZ (B_SZ * T_SZ)              // 9600
#define N_PAD 448                       // a1 row stride = gemm1 N (7 x 64)
#define KW (F_IN / 32)                  // 96 bit-words per spike row
#define TOTAL_ELEMS (B_SZ * T_SZ * F_IN)
#define N_WORDS (TOTAL_ELEMS / 32)      // 921600
#define A2_STRIDE 16
#define NCHUNK 10
#define CLEN 30
#define NKB (F_IN / 256)                // 12 K-blocks of 256
#define MT_CNT (M_SZ / 64)              // 150 m-tiles
#define W1_BLOCKS 672                   // 448*3072/8/256
#define RNG_BLOCKS 3600                 // 921600/256

// f32(exp(f32(-0.1))) — PSP decay, matches XLA's correctly-rounded exp
#define DECAY 0.90483741803595957f
#define THETA 10.0f

typedef __attribute__((ext_vector_type(8))) int i32x8;
typedef __attribute__((ext_vector_type(16))) float f32x16;

__device__ __forceinline__ uint32_t rotl32(uint32_t x, uint32_t r) {
  return (x << r) | (x >> (32u - r));
}

// JAX threefry2x32, key = (0, 42)
__device__ __forceinline__ void threefry2x32(uint32_t& x0, uint32_t& x1) {
  const uint32_t ks0 = 0u;
  const uint32_t ks1 = 42u;
  const uint32_t ks2 = 0x1BD11BDAu ^ 0u ^ 42u;
  x0 += ks0; x1 += ks1;
#define TF_ROUND(r) { x0 += x1; x1 = rotl32(x1, (r)); x1 ^= x0; }
  TF_ROUND(13) TF_ROUND(15) TF_ROUND(26) TF_ROUND(6)
  x0 += ks1; x1 += ks2 + 1u;
  TF_ROUND(17) TF_ROUND(29) TF_ROUND(16) TF_ROUND(24)
  x0 += ks2; x1 += ks0 + 2u;
  TF_ROUND(13) TF_ROUND(15) TF_ROUND(26) TF_ROUND(6)
  x0 += ks0; x1 += ks1 + 3u;
  TF_ROUND(17) TF_ROUND(29) TF_ROUND(16) TF_ROUND(24)
  x0 += ks1; x1 += ks2 + 4u;
  TF_ROUND(13) TF_ROUND(15) TF_ROUND(26) TF_ROUND(6)
  x0 += ks2; x1 += ks0 + 5u;
#undef TF_ROUND
}

__device__ __forceinline__ float u01(uint32_t bits) {
  return __uint_as_float((bits >> 9) | 0x3F800000u) - 1.0f;
}

// async global->LDS, 16 B per lane; LDS dest = wave-uniform base + lane*16
__device__ __forceinline__ void gld16(const void* g, void* l) {
  __builtin_amdgcn_global_load_lds(
      (const __attribute__((address_space(1))) uint32_t*)g,
      (__attribute__((address_space(3))) uint32_t*)l, 16, 0, 0);
}

// Merged prep.
// Blocks [0, 672): W1 fp32 -> e4m3, stored PRE-SWIZZLED in the gemm1 LDS
//   image layout W1s[nt][kb][row r][chunk c^(r&15)]*16B (rows >= 410 zeroed),
//   so global_load_lds DMA produces a conflict-free LDS tile directly.
// Blocks [672, 4272): partitionable threefry rate-encode (ctr=(0,i),
//   bits=o0^o1), output TILE-TRANSPOSED: sbitsT[mt][kb][word wi][row r]
//   (writes coalesced; gemm1 A-DMA is a straight copy).
__global__ __launch_bounds__(256) void prep(const float* __restrict__ inp,
                                            const float* __restrict__ W1,
                                            uint8_t* __restrict__ W1s,
                                            uint32_t* __restrict__ sbitsT) {
  if (blockIdx.x < W1_BLOCKS) {
    int idx = blockIdx.x * 256 + threadIdx.x;
    int g = idx * 8;
    int n = g / F_IN;
    int k = g - n * F_IN;
    uint32_t d0 = 0u, d1 = 0u;
    if (n < F_HID) {
      const float* s = W1 + (size_t)n * F_IN + k;
      float4 v0 = ((const float4*)s)[0];
      float4 v1 = ((const float4*)s)[1];
      int t0 = __builtin_amdgcn_cvt_pk_fp8_f32(v0.x, v0.y, 0, false);
      t0 = __builtin_amdgcn_cvt_pk_fp8_f32(v0.z, v0.w, t0, true);
      int t1 = __builtin_amdgcn_cvt_pk_fp8_f32(v1.x, v1.y, 0, false);
      t1 = __builtin_amdgcn_cvt_pk_fp8_f32(v1.z, v1.w, t1, true);
      d0 = (uint32_t)t0; d1 = (uint32_t)t1;
    }
    int nt = n >> 6, r = n & 63;
    int kb = k >> 8, c = (k >> 4) & 15, half = (k >> 3) & 1;
    size_t dst = ((((size_t)nt * NKB + kb) * 64 + r) * 16 + (c ^ (r & 15))) * 16 + half * 8;
    *(uint2*)(W1s + dst) = make_uint2(d0, d1);
  } else {
    uint32_t j = (blockIdx.x - W1_BLOCKS) * 256u + threadIdx.x;  // [0, 921600)
    uint32_t r = j & 63u;
    uint32_t t1 = j >> 6;
    uint32_t wi = t1 & 7u;
    uint32_t t2 = t1 >> 3;          // (mt*12 + kb) in [0, 1800)
    uint32_t kb = t2 % (uint32_t)NKB;
    uint32_t mt = t2 / (uint32_t)NKB;
    uint32_t m = mt * 64u + r;      // GEMM row = b*300 + t
    uint32_t b = m / (uint32_t)T_SZ;
    uint32_t f = (kb * 8u + wi) * 32u;
    const float* p = inp + b * F_IN + f;
    float pr[32];
#pragma unroll
    for (int q = 0; q < 8; ++q) {
      float4 v = ((const float4*)p)[q];
      pr[q * 4 + 0] = v.x; pr[q * 4 + 1] = v.y; pr[q * 4 + 2] = v.z; pr[q * 4 + 3] = v.w;
    }
    uint32_t base = m * (uint32_t)F_IN + f;   // flat counter index of bit 0
    uint32_t w = 0u;
#pragma unroll
    for (uint32_t k = 0; k < 32u; ++k) {
      uint32_t x0 = 0u, x1 = base + k;
      threefry2x32(x0, x1);
      float u = u01(x0 ^ x1);
      w |= (u < pr[k]) ? (1u << k) : 0u;
    }
    sbitsT[j] = w;   // j already enumerates [mt][kb][wi][r] order
  }
}

// a1[m][n] = sum_k spike(m,k)*W1[n][k], MX-fp8 MFMA 32x32x64 (scales=127=2^0).
// BM=64, BN=64, BK=256, grid 150x7=1050, 256 thr = 4 waves (2x2 of 32x32).
// ALL staging via global_load_lds (no staging VGPRs -> no spill, the R5/R6
// failure mode). W1s is pre-swizzled in memory; sbitsT pre-transposed. A bits
// expanded to fp8 at frag read (mul-spread). acc = 16 AGPR.
__global__ __launch_bounds__(256) void gemm1(const uint32_t* __restrict__ sbitsT,
                                             const uint8_t* __restrict__ W1s,
                                             float* __restrict__ a1) {
  __shared__ uint32_t sAT[8 * 64];   // 2 KB: [word][row]
  __shared__ uint8_t sB[64 * 256];   // 16 KB: swizzled LDS image

  const int tid = threadIdx.x;
  const int mtile = blockIdx.x;
  const int nt = blockIdx.y;
  const int m0 = mtile * 64;
  const int n0 = nt * 64;
  const int wv = tid >> 6, lane = tid & 63;
  const int wm = (wv & 1) * 32, wn = (wv >> 1) * 32;
  const int l31 = lane & 31, lh = lane >> 5;

  const uint8_t* gB0 = W1s + (size_t)nt * NKB * 16384;
  const uint8_t* gA0 = (const uint8_t*)sbitsT + (size_t)mtile * NKB * 2048;

  f32x16 acc;
#pragma unroll
  for (int e = 0; e < 16; ++e) acc[e] = 0.0f;

  for (int kb = 0; kb < NKB; ++kb) {
    // DMA this kb's tiles straight into LDS (4 B-issues/wave + A by waves 0,1)
    const uint8_t* gB = gB0 + (size_t)kb * 16384;
#pragma unroll
    for (int q = 0; q < 4; ++q)
      gld16(gB + (wv * 4 + q) * 1024 + lane * 16, &sB[(wv * 4 + q) * 1024]);
    if (wv < 2)
      gld16(gA0 + (size_t)kb * 2048 + wv * 1024 + lane * 16,
            (uint8_t*)sAT + wv * 1024);
    __syncthreads();   // vmcnt drain + visibility
#pragma unroll
    for (int sub = 0; sub < 4; ++sub) {
      // B frag: B[n = wn+l31][k = sub*64 + lh*32 + 0..31]
      int row = wn + l31;
      int cb = sub * 4 + lh * 2;
      uint4 u0 = *(uint4*)&sB[row * 256 + (((cb + 0) ^ (row & 15)) << 4)];
      uint4 u1 = *(uint4*)&sB[row * 256 + (((cb + 1) ^ (row & 15)) << 4)];
      i32x8 bfr;
      bfr[0] = u0.x; bfr[1] = u0.y; bfr[2] = u0.z; bfr[3] = u0.w;
      bfr[4] = u1.x; bfr[5] = u1.y; bfr[6] = u1.z; bfr[7] = u1.w;
      // A frag: A[m = wm+l31][same k], expanded bits -> fp8(1.0)=0x38
      uint32_t w = sAT[(sub * 2 + lh) * 64 + wm + l31];
      i32x8 afr;
#pragma unroll
      for (int j = 0; j < 8; ++j) {
        uint32_t n = (w >> (4 * j)) & 15u;
        afr[j] = (int)(((n * 0x204081u) & 0x01010101u) * 0x38u);
      }
      acc = __builtin_amdgcn_mfma_scale_f32_32x32x64_f8f6f4(
          afr, bfr, acc, 0, 0, 0, 127, 0, 127);
    }
    __syncthreads();   // LDS free before next kb's DMA
  }
  // epilogue: C/D 32x32: col = lane&31, row = (reg&3) + 8*(reg>>2) + 4*(lane>>5)
  int col = n0 + wn + l31;
#pragma unroll
  for (int rg = 0; rg < 16; ++rg) {
    int row = m0 + wm + (rg & 3) + 8 * (rg >> 2) + 4 * lh;
    a1[(size_t)row * N_PAD + col] = acc[rg];
  }
}

// PSP phase A: per-(b,chunk,o) partial scan from 0; partials overwrite a1;
// raw chunk finals pf -> fin[b][c][o].
__global__ __launch_bounds__(256) void psp1_partial(float* __restrict__ a1,
                                                    float* __restrict__ fin) {
  int idx = blockIdx.x * 256 + threadIdx.x;   // 32*10*448 = 143360
  if (idx >= B_SZ * NCHUNK * N_PAD) return;
  int o = idx % N_PAD;
  int bc = idx / N_PAD;
  int c = bc % NCHUNK;
  int b = bc / NCHUNK;
  float* p = a1 + ((size_t)(b * T_SZ + c * CLEN)) * N_PAD + o;
  float u = 0.0f;
#pragma unroll
  for (int i = 0; i < CLEN; ++i) {
    u = __fadd_rn(__fmul_rn(DECAY, u), p[(size_t)i * N_PAD]);
    p[(size_t)i * N_PAD] = u;
  }
  fin[(size_t)bc * N_PAD + o] = u;
}

// Fused chunk-combine + PSP apply + layer-2 GEMM. One wave per (b,t).
// F(c-1) computed on the fly from raw pf (same recurrence order as the old
// psp1_combine: F = pf[cc] + d30*F, cc ascending -> bit-identical).
__global__ __launch_bounds__(256) void apply_gemm2(const float* __restrict__ a1,
                                                   const float* __restrict__ fin,
                                                   const float* __restrict__ W2,
                                                   float* __restrict__ a2) {
  __shared__ float sW2[F_OUT * F_HID];   // 16.4 KB
  for (int i = threadIdx.x; i < F_OUT * F_HID; i += 256) sW2[i] = W2[i];
  __syncthreads();
  int m = blockIdx.x * 4 + (threadIdx.x >> 6);
  int lane = threadIdx.x & 63;
  int b = m / T_SZ, t = m % T_SZ;
  int c = t / CLEN, tl = t % CLEN;
  float d30 = 1.0f;
#pragma unroll
  for (int i = 0; i < CLEN; ++i) d30 *= DECAY;
  float dp = DECAY;
  for (int i = 0; i < tl; ++i) dp *= DECAY;   // decay^(tl+1), wave-uniform
  float p[F_OUT];
#pragma unroll
  for (int o = 0; o < F_OUT; ++o) p[o] = 0.0f;
#pragma unroll
  for (int j = 0; j < 7; ++j) {
    int hh = lane + j * 64;
    float u = a1[(size_t)m * N_PAD + hh];
    if (c > 0) {
      float F = 0.0f;
      const float* f = fin + (size_t)b * NCHUNK * N_PAD + hh;
      for (int cc = 0; cc < c; ++cc)          // wave-uniform trip count
        F = f[(size_t)cc * N_PAD] + d30 * F;
      u = __fadd_rn(u, __fmul_rn(dp, F));
    }
    bool valid = hh < F_HID;
    float s = (u >= THETA && valid) ? 1.0f : 0.0f;
    int hcl = valid ? hh : 0;
#pragma unroll
    for (int o = 0; o < F_OUT; ++o) p[o] = fmaf(s, sW2[o * F_HID + hcl], p[o]);
  }
#pragma unroll
  for (int o = 0; o < F_OUT; ++o)
#pragma unroll
    for (int s = 1; s < 64; s <<= 1) p[o] += __shfl_xor(p[o], s, 64);
  if (lane < F_OUT) a2[(size_t)m * A2_STRIDE + lane] = p[lane];
}

// Layer-2 PSP, chunked, one block per batch; lanes (o,c) in [10x10].
__global__ __launch_bounds__(128) void psp2(const float* __restrict__ a2,
                                            float* __restrict__ out) {
  __shared__ float chf[NCHUNK][F_OUT];
  __shared__ float seed[NCHUNK][F_OUT];
  int b = blockIdx.x;
  int tid = threadIdx.x;
  int o = tid / NCHUNK, c = tid % NCHUNK;
  const float* p = a2 + ((size_t)(b * T_SZ + c * CLEN)) * A2_STRIDE + o;
  float v[CLEN];
  float pa[CLEN];
  if (tid < F_OUT * NCHUNK) {
#pragma unroll
    for (int i = 0; i < CLEN; ++i) v[i] = p[(size_t)i * A2_STRIDE];
    float u = 0.0f;
#pragma unroll
    for (int i = 0; i < CLEN; ++i) {
      u = __fadd_rn(__fmul_rn(DECAY, u), v[i]);
      pa[i] = u;
    }
    chf[c][o] = u;
  }
  __syncthreads();
  if (tid < F_OUT) {
    float d30 = 1.0f;
#pragma unroll
    for (int i = 0; i < CLEN; ++i) d30 *= DECAY;
    float F = 0.0f;
    for (int cc = 0; cc < NCHUNK; ++cc) {
      F = chf[cc][tid] + d30 * F;
      seed[cc][tid] = F;
    }
  }
  __syncthreads();
  if (tid < F_OUT * NCHUNK) {
    float F = (c == 0) ? 0.0f : seed[c - 1][o];
    float dp = DECAY;
    float* q = out + (size_t)b * F_OUT * T_SZ + (size_t)o * T_SZ + c * CLEN;
#pragma unroll
    for (int i = 0; i < CLEN; ++i) {
      float u = (c == 0) ? pa[i] : __fadd_rn(pa[i], __fmul_rn(dp, F));
      q[i] = (u >= THETA) ? 1.0f : 0.0f;
      dp *= DECAY;
    }
  }
}

extern "C" void kernel_launch(void* const* d_in, const int* in_sizes, int n_in,
                              void* d_out, int out_size, void* d_ws, size_t ws_size,
                              hipStream_t stream) {
  const float* inp = (const float*)d_in[0];  // [32,3,32,32]
  const float* W1  = (const float*)d_in[1];  // [410,3072]
  const float* W2  = (const float*)d_in[2];  // [10,410]
  float* out = (float*)d_out;                // [32,10,300]
  char* ws = (char*)d_ws;
  // ws: W1s 1376256 | sbitsT 3686400 | a1 17203200 | fin 573440 | a2 614400
  uint8_t* W1s = (uint8_t*)(ws);
  uint32_t* sbitsT = (uint32_t*)(ws + 1376256);
  float* a1 = (float*)(ws + 1376256 + 3686400);
  float* fin = a1 + (size_t)M_SZ * N_PAD;
  float* a2 = fin + (size_t)B_SZ * NCHUNK * N_PAD;

  prep<<<dim3(W1_BLOCKS + RNG_BLOCKS), dim3(256), 0, stream>>>(inp, W1, W1s, sbitsT);
  gemm1<<<dim3(MT_CNT, N_PAD / 64), dim3(256), 0, stream>>>(sbitsT, W1s, a1);
  psp1_partial<<<dim3((B_SZ * NCHUNK * N_PAD) / 256), dim3(256), 0, stream>>>(a1, fin);
  apply_gemm2<<<dim3(M_SZ / 4), dim3(256), 0, stream>>>(a1, fin, W2, a2);
  psp2<<<dim3(B_SZ), dim3(128), 0, stream>>>(a2, out);
}

// Round 8
// 180.321 us; speedup vs baseline: 1.3419x; 1.0053x over previous
//
#include <hip/hip_runtime.h>
#include <stdint.h>

#define B_SZ 32
#define T_SZ 300
#define F_IN 3072
#define F_HID 410
#define F_OUT 10
#define M_SZ (B_SZ * T_SZ)              // 9600
#define N_PAD 448                       // a1 row stride = gemm1 N (7 x 64)
#define KW (F_IN / 32)                  // 96 bit-words per spike row
#define TOTAL_ELEMS (B_SZ * T_SZ * F_IN)
#define N_WORDS (TOTAL_ELEMS / 32)      // 921600
#define A2_STRIDE 16
#define NCHUNK 10
#define CLEN 30
#define NKB (F_IN / 256)                // 12 K-blocks of 256
#define MT_CNT (M_SZ / 64)              // 150 m-tiles
#define W1_BLOCKS 672                   // 448*3072/8/256
#define RNG_BLOCKS 3600                 // 921600/256

// f32(exp(f32(-0.1))) — PSP decay, matches XLA's correctly-rounded exp
#define DECAY 0.90483741803595957f
#define THETA 10.0f

typedef __attribute__((ext_vector_type(8))) int i32x8;
typedef __attribute__((ext_vector_type(16))) float f32x16;

// rotl via v_alignbit_b32 (alignbit(x,x,s) = rotr(x,s); rotl r = rotr 32-r).
// The generic (x<<r)|(x>>(32-r)) was not reliably lowered to alignbit --
// 5 VALU/round instead of 3, ~35% of prep's runtime.
#define ROTL(x, r) __builtin_amdgcn_alignbit((x), (x), 32u - (r))

// JAX threefry2x32, key = (0, 42)
__device__ __forceinline__ void threefry2x32(uint32_t& x0, uint32_t& x1) {
  const uint32_t ks0 = 0u;
  const uint32_t ks1 = 42u;
  const uint32_t ks2 = 0x1BD11BDAu ^ 0u ^ 42u;
  x0 += ks0; x1 += ks1;
#define TF_ROUND(r) { x0 += x1; x1 = ROTL(x1, (r)); x1 ^= x0; }
  TF_ROUND(13) TF_ROUND(15) TF_ROUND(26) TF_ROUND(6)
  x0 += ks1; x1 += ks2 + 1u;
  TF_ROUND(17) TF_ROUND(29) TF_ROUND(16) TF_ROUND(24)
  x0 += ks2; x1 += ks0 + 2u;
  TF_ROUND(13) TF_ROUND(15) TF_ROUND(26) TF_ROUND(6)
  x0 += ks0; x1 += ks1 + 3u;
  TF_ROUND(17) TF_ROUND(29) TF_ROUND(16) TF_ROUND(24)
  x0 += ks1; x1 += ks2 + 4u;
  TF_ROUND(13) TF_ROUND(15) TF_ROUND(26) TF_ROUND(6)
  x0 += ks2; x1 += ks0 + 5u;
#undef TF_ROUND
}

__device__ __forceinline__ float u01(uint32_t bits) {
  return __uint_as_float((bits >> 9) | 0x3F800000u) - 1.0f;
}

// async global->LDS, 16 B per lane; LDS dest = wave-uniform base + lane*16
__device__ __forceinline__ void gld16(const void* g, void* l) {
  __builtin_amdgcn_global_load_lds(
      (const __attribute__((address_space(1))) uint32_t*)g,
      (__attribute__((address_space(3))) uint32_t*)l, 16, 0, 0);
}

// Merged prep.
// Blocks [0, 672): W1 fp32 -> e4m3, stored PRE-SWIZZLED in the gemm1 LDS
//   image layout W1s[nt][kb][row r][chunk c^(r&15)]*16B (rows >= 410 zeroed),
//   so global_load_lds DMA produces a conflict-free LDS tile directly.
// Blocks [672, 4272): partitionable threefry rate-encode (ctr=(0,i),
//   bits=o0^o1), output TILE-TRANSPOSED: sbitsT[mt][kb][word wi][row r]
//   (writes coalesced; gemm1 A-DMA is a straight copy).
__global__ __launch_bounds__(256) void prep(const float* __restrict__ inp,
                                            const float* __restrict__ W1,
                                            uint8_t* __restrict__ W1s,
                                            uint32_t* __restrict__ sbitsT) {
  if (blockIdx.x < W1_BLOCKS) {
    int idx = blockIdx.x * 256 + threadIdx.x;
    int g = idx * 8;
    int n = g / F_IN;
    int k = g - n * F_IN;
    uint32_t d0 = 0u, d1 = 0u;
    if (n < F_HID) {
      const float* s = W1 + (size_t)n * F_IN + k;
      float4 v0 = ((const float4*)s)[0];
      float4 v1 = ((const float4*)s)[1];
      int t0 = __builtin_amdgcn_cvt_pk_fp8_f32(v0.x, v0.y, 0, false);
      t0 = __builtin_amdgcn_cvt_pk_fp8_f32(v0.z, v0.w, t0, true);
      int t1 = __builtin_amdgcn_cvt_pk_fp8_f32(v1.x, v1.y, 0, false);
      t1 = __builtin_amdgcn_cvt_pk_fp8_f32(v1.z, v1.w, t1, true);
      d0 = (uint32_t)t0; d1 = (uint32_t)t1;
    }
    int nt = n >> 6, r = n & 63;
    int kb = k >> 8, c = (k >> 4) & 15, half = (k >> 3) & 1;
    size_t dst = ((((size_t)nt * NKB + kb) * 64 + r) * 16 + (c ^ (r & 15))) * 16 + half * 8;
    *(uint2*)(W1s + dst) = make_uint2(d0, d1);
  } else {
    uint32_t j = (blockIdx.x - W1_BLOCKS) * 256u + threadIdx.x;  // [0, 921600)
    uint32_t r = j & 63u;
    uint32_t t1 = j >> 6;
    uint32_t wi = t1 & 7u;
    uint32_t t2 = t1 >> 3;          // (mt*12 + kb) in [0, 1800)
    uint32_t kb = t2 % (uint32_t)NKB;
    uint32_t mt = t2 / (uint32_t)NKB;
    uint32_t m = mt * 64u + r;      // GEMM row = b*300 + t
    uint32_t b = m / (uint32_t)T_SZ;
    uint32_t f = (kb * 8u + wi) * 32u;
    const float* p = inp + b * F_IN + f;
    float pr[32];
#pragma unroll
    for (int q = 0; q < 8; ++q) {
      float4 v = ((const float4*)p)[q];
      pr[q * 4 + 0] = v.x; pr[q * 4 + 1] = v.y; pr[q * 4 + 2] = v.z; pr[q * 4 + 3] = v.w;
    }
    uint32_t base = m * (uint32_t)F_IN + f;   // flat counter index of bit 0
    uint32_t w = 0u;
#pragma unroll
    for (uint32_t k = 0; k < 32u; ++k) {
      uint32_t x0 = 0u, x1 = base + k;
      threefry2x32(x0, x1);
      float u = u01(x0 ^ x1);
      w |= (u < pr[k]) ? (1u << k) : 0u;
    }
    sbitsT[j] = w;   // j already enumerates [mt][kb][wi][r] order
  }
}

// a1[m][n] = sum_k spike(m,k)*W1[n][k], MX-fp8 MFMA 32x32x64 (scales=127=2^0).
// BM=64, BN=64, BK=256, grid 150x7=1050, 256 thr = 4 waves (2x2 of 32x32).
// ALL staging via global_load_lds (no staging VGPRs -> no spill, the R5/R6
// failure mode). W1s is pre-swizzled in memory; sbitsT pre-transposed. A bits
// expanded to fp8 at frag read (mul-spread). acc = 16 AGPR.
__global__ __launch_bounds__(256) void gemm1(const uint32_t* __restrict__ sbitsT,
                                             const uint8_t* __restrict__ W1s,
                                             float* __restrict__ a1) {
  __shared__ uint32_t sAT[8 * 64];   // 2 KB: [word][row]
  __shared__ uint8_t sB[64 * 256];   // 16 KB: swizzled LDS image

  const int tid = threadIdx.x;
  const int mtile = blockIdx.x;
  const int nt = blockIdx.y;
  const int m0 = mtile * 64;
  const int n0 = nt * 64;
  const int wv = tid >> 6, lane = tid & 63;
  const int wm = (wv & 1) * 32, wn = (wv >> 1) * 32;
  const int l31 = lane & 31, lh = lane >> 5;

  const uint8_t* gB0 = W1s + (size_t)nt * NKB * 16384;
  const uint8_t* gA0 = (const uint8_t*)sbitsT + (size_t)mtile * NKB * 2048;

  f32x16 acc;
#pragma unroll
  for (int e = 0; e < 16; ++e) acc[e] = 0.0f;

  for (int kb = 0; kb < NKB; ++kb) {
    // DMA this kb's tiles straight into LDS (4 B-issues/wave + A by waves 0,1)
    const uint8_t* gB = gB0 + (size_t)kb * 16384;
#pragma unroll
    for (int q = 0; q < 4; ++q)
      gld16(gB + (wv * 4 + q) * 1024 + lane * 16, &sB[(wv * 4 + q) * 1024]);
    if (wv < 2)
      gld16(gA0 + (size_t)kb * 2048 + wv * 1024 + lane * 16,
            (uint8_t*)sAT + wv * 1024);
    __syncthreads();   // vmcnt drain + visibility
#pragma unroll
    for (int sub = 0; sub < 4; ++sub) {
      // B frag: B[n = wn+l31][k = sub*64 + lh*32 + 0..31]
      int row = wn + l31;
      int cb = sub * 4 + lh * 2;
      uint4 u0 = *(uint4*)&sB[row * 256 + (((cb + 0) ^ (row & 15)) << 4)];
      uint4 u1 = *(uint4*)&sB[row * 256 + (((cb + 1) ^ (row & 15)) << 4)];
      i32x8 bfr;
      bfr[0] = u0.x; bfr[1] = u0.y; bfr[2] = u0.z; bfr[3] = u0.w;
      bfr[4] = u1.x; bfr[5] = u1.y; bfr[6] = u1.z; bfr[7] = u1.w;
      // A frag: A[m = wm+l31][same k], expanded bits -> fp8(1.0)=0x38
      uint32_t w = sAT[(sub * 2 + lh) * 64 + wm + l31];
      i32x8 afr;
#pragma unroll
      for (int j = 0; j < 8; ++j) {
        uint32_t n = (w >> (4 * j)) & 15u;
        afr[j] = (int)(((n * 0x204081u) & 0x01010101u) * 0x38u);
      }
      acc = __builtin_amdgcn_mfma_scale_f32_32x32x64_f8f6f4(
          afr, bfr, acc, 0, 0, 0, 127, 0, 127);
    }
    __syncthreads();   // LDS free before next kb's DMA
  }
  // epilogue: C/D 32x32: col = lane&31, row = (reg&3) + 8*(reg>>2) + 4*(lane>>5)
  int col = n0 + wn + l31;
#pragma unroll
  for (int rg = 0; rg < 16; ++rg) {
    int row = m0 + wm + (rg & 3) + 8 * (rg >> 2) + 4 * lh;
    a1[(size_t)row * N_PAD + col] = acc[rg];
  }
}

// PSP phase A: per-(b,chunk,o) partial scan from 0; partials overwrite a1;
// raw chunk finals pf -> fin[b][c][o].
__global__ __launch_bounds__(256) void psp1_partial(float* __restrict__ a1,
                                                    float* __restrict__ fin) {
  int idx = blockIdx.x * 256 + threadIdx.x;   // 32*10*448 = 143360
  if (idx >= B_SZ * NCHUNK * N_PAD) return;
  int o = idx % N_PAD;
  int bc = idx / N_PAD;
  int c = bc % NCHUNK;
  int b = bc / NCHUNK;
  float* p = a1 + ((size_t)(b * T_SZ + c * CLEN)) * N_PAD + o;
  float u = 0.0f;
#pragma unroll
  for (int i = 0; i < CLEN; ++i) {
    u = __fadd_rn(__fmul_rn(DECAY, u), p[(size_t)i * N_PAD]);
    p[(size_t)i * N_PAD] = u;
  }
  fin[(size_t)bc * N_PAD + o] = u;
}

// Fused chunk-combine + PSP apply + layer-2 GEMM. One wave per (b,t).
// F(c-1) computed on the fly from raw pf (same recurrence order as the old
// psp1_combine: F = pf[cc] + d30*F, cc ascending -> bit-identical).
__global__ __launch_bounds__(256) void apply_gemm2(const float* __restrict__ a1,
                                                   const float* __restrict__ fin,
                                                   const float* __restrict__ W2,
                                                   float* __restrict__ a2) {
  __shared__ float sW2[F_OUT * F_HID];   // 16.4 KB
  for (int i = threadIdx.x; i < F_OUT * F_HID; i += 256) sW2[i] = W2[i];
  __syncthreads();
  int m = blockIdx.x * 4 + (threadIdx.x >> 6);
  int lane = threadIdx.x & 63;
  int b = m / T_SZ, t = m % T_SZ;
  int c = t / CLEN, tl = t % CLEN;
  float d30 = 1.0f;
#pragma unroll
  for (int i = 0; i < CLEN; ++i) d30 *= DECAY;
  float dp = DECAY;
  for (int i = 0; i < tl; ++i) dp *= DECAY;   // decay^(tl+1), wave-uniform
  float p[F_OUT];
#pragma unroll
  for (int o = 0; o < F_OUT; ++o) p[o] = 0.0f;
#pragma unroll
  for (int j = 0; j < 7; ++j) {
    int hh = lane + j * 64;
    float u = a1[(size_t)m * N_PAD + hh];
    if (c > 0) {
      float F = 0.0f;
      const float* f = fin + (size_t)b * NCHUNK * N_PAD + hh;
      for (int cc = 0; cc < c; ++cc)          // wave-uniform trip count
        F = f[(size_t)cc * N_PAD] + d30 * F;
      u = __fadd_rn(u, __fmul_rn(dp, F));
    }
    bool valid = hh < F_HID;
    float s = (u >= THETA && valid) ? 1.0f : 0.0f;
    int hcl = valid ? hh : 0;
#pragma unroll
    for (int o = 0; o < F_OUT; ++o) p[o] = fmaf(s, sW2[o * F_HID + hcl], p[o]);
  }
#pragma unroll
  for (int o = 0; o < F_OUT; ++o)
#pragma unroll
    for (int s = 1; s < 64; s <<= 1) p[o] += __shfl_xor(p[o], s, 64);
  if (lane < F_OUT) a2[(size_t)m * A2_STRIDE + lane] = p[lane];
}

// Layer-2 PSP, chunked, one block per batch; lanes (o,c) in [10x10].
__global__ __launch_bounds__(128) void psp2(const float* __restrict__ a2,
                                            float* __restrict__ out) {
  __shared__ float chf[NCHUNK][F_OUT];
  __shared__ float seed[NCHUNK][F_OUT];
  int b = blockIdx.x;
  int tid = threadIdx.x;
  int o = tid / NCHUNK, c = tid % NCHUNK;
  const float* p = a2 + ((size_t)(b * T_SZ + c * CLEN)) * A2_STRIDE + o;
  float v[CLEN];
  float pa[CLEN];
  if (tid < F_OUT * NCHUNK) {
#pragma unroll
    for (int i = 0; i < CLEN; ++i) v[i] = p[(size_t)i * A2_STRIDE];
    float u = 0.0f;
#pragma unroll
    for (int i = 0; i < CLEN; ++i) {
      u = __fadd_rn(__fmul_rn(DECAY, u), v[i]);
      pa[i] = u;
    }
    chf[c][o] = u;
  }
  __syncthreads();
  if (tid < F_OUT) {
    float d30 = 1.0f;
#pragma unroll
    for (int i = 0; i < CLEN; ++i) d30 *= DECAY;
    float F = 0.0f;
    for (int cc = 0; cc < NCHUNK; ++cc) {
      F = chf[cc][tid] + d30 * F;
      seed[cc][tid] = F;
    }
  }
  __syncthreads();
  if (tid < F_OUT * NCHUNK) {
    float F = (c == 0) ? 0.0f : seed[c - 1][o];
    float dp = DECAY;
    float* q = out + (size_t)b * F_OUT * T_SZ + (size_t)o * T_SZ + c * CLEN;
#pragma unroll
    for (int i = 0; i < CLEN; ++i) {
      float u = (c == 0) ? pa[i] : __fadd_rn(pa[i], __fmul_rn(dp, F));
      q[i] = (u >= THETA) ? 1.0f : 0.0f;
      dp *= DECAY;
    }
  }
}

extern "C" void kernel_launch(void* const* d_in, const int* in_sizes, int n_in,
                              void* d_out, int out_size, void* d_ws, size_t ws_size,
                              hipStream_t stream) {
  const float* inp = (const float*)d_in[0];  // [32,3,32,32]
  const float* W1  = (const float*)d_in[1];  // [410,3072]
  const float* W2  = (const float*)d_in[2];  // [10,410]
  float* out = (float*)d_out;                // [32,10,300]
  char* ws = (char*)d_ws;
  // ws: W1s 1376256 | sbitsT 3686400 | a1 17203200 | fin 573440 | a2 614400
  uint8_t* W1s = (uint8_t*)(ws);
  uint32_t* sbitsT = (uint32_t*)(ws + 1376256);
  float* a1 = (float*)(ws + 1376256 + 3686400);
  float* fin = a1 + (size_t)M_SZ * N_PAD;
  float* a2 = fin + (size_t)B_SZ * NCHUNK * N_PAD;

  prep<<<dim3(W1_BLOCKS + RNG_BLOCKS), dim3(256), 0, stream>>>(inp, W1, W1s, sbitsT);
  gemm1<<<dim3(MT_CNT, N_PAD / 64), dim3(256), 0, stream>>>(sbitsT, W1s, a1);
  psp1_partial<<<dim3((B_SZ * NCHUNK * N_PAD) / 256), dim3(256), 0, stream>>>(a1, fin);
  apply_gemm2<<<dim3(M_SZ / 4), dim3(256), 0, stream>>>(a1, fin, W2, a2);
  psp2<<<dim3(B_SZ), dim3(128), 0, stream>>>(a2, out);
}